// Round 5
// baseline (129.324 us; speedup 1.0000x reference)
//
#include <hip/hip_runtime.h>
#include <stdint.h>

// CrossAttentionLayer: B=2, Q=256, N=16384, C=256, H=8, d=32
#define B_ 2
#define Q_ 256
#define N_ 16384
#define C_ 256
#define H_ 8
#define D_ 32
#define NC_ 16                      // attention split-N chunks (N/NC = 1024 per block)
#define SCALE 0.17677669529663687f  // 1/sqrt(32)

typedef __bf16 bf16x8 __attribute__((ext_vector_type(8)));
typedef float f32x4 __attribute__((ext_vector_type(4)));

__device__ __forceinline__ uint16_t f2bf(float f) {
  union { float f; uint32_t u; } c; c.f = f;
  uint32_t r = c.u + 0x7FFFu + ((c.u >> 16) & 1u);  // RNE
  return (uint16_t)(r >> 16);
}
__device__ __forceinline__ uint32_t pk2(float a, float b) {
  return (uint32_t)f2bf(a) | ((uint32_t)f2bf(b) << 16);
}
__device__ __forceinline__ void lgkm0_barrier() {
  __builtin_amdgcn_sched_barrier(0);
  asm volatile("s_waitcnt lgkmcnt(0)" ::: "memory");
  __builtin_amdgcn_sched_barrier(0);
  __builtin_amdgcn_s_barrier();
  __builtin_amdgcn_sched_barrier(0);
}

// ---------------------------------------------------------------------------
// Kernel 0a: convert K/V projection weights (in_proj_w rows 256..767) to bf16.
// wkv row r = in_proj_w row 256+r: rows 0..255 = wk, 256..511 = wv.
// ---------------------------------------------------------------------------
__global__ __launch_bounds__(256) void wprep(const float* __restrict__ w,
                                             uint16_t* __restrict__ wb) {
  const int i = (blockIdx.x * 256 + threadIdx.x) * 8;
  const float* src = w + 256 * C_ + i;
  float4 a = *reinterpret_cast<const float4*>(src);
  float4 b = *reinterpret_cast<const float4*>(src + 4);
  ushort4 lo = {f2bf(a.x), f2bf(a.y), f2bf(a.z), f2bf(a.w)};
  ushort4 hi = {f2bf(b.x), f2bf(b.y), f2bf(b.z), f2bf(b.w)};
  *reinterpret_cast<ushort4*>(wb + i) = lo;
  *reinterpret_cast<ushort4*>(wb + i + 4) = hi;
}

// ---------------------------------------------------------------------------
// Kernel 0b: 256x256 fp32 transpose (for wq and wo -> coalesced dot products).
// ---------------------------------------------------------------------------
__global__ __launch_bounds__(256) void transpose256(const float* __restrict__ src,
                                                    float* __restrict__ dst) {
  __shared__ float s[32][33];
  const int bx = blockIdx.x & 7, by = blockIdx.x >> 3;
  const int r0 = by * 32, c0 = bx * 32;
  const int tr = threadIdx.x >> 5, tc = threadIdx.x & 31;
#pragma unroll
  for (int k = 0; k < 4; ++k) s[tr + 8 * k][tc] = src[(size_t)(r0 + tr + 8 * k) * 256 + c0 + tc];
  __syncthreads();
#pragma unroll
  for (int k = 0; k < 4; ++k) dst[(size_t)(c0 + tr + 8 * k) * 256 + r0 + tc] = s[tc][tr + 8 * k];
}

// ---------------------------------------------------------------------------
// Kernel 1: pack vid_mask (B,Q,N) fp32 -> bitmask (B,Q,N/32), bit=1 => blocked.
// ---------------------------------------------------------------------------
__global__ __launch_bounds__(256) void pack_mask(const float* __restrict__ vm,
                                                 uint32_t* __restrict__ mb) {
  const int bq = blockIdx.x;
  const float* row = vm + (size_t)bq * N_;
  const int t = threadIdx.x, lane = t & 63;
  __shared__ uint8_t nib[16][256];
  __shared__ int wcnt[4];
  __shared__ int tot;
  int cnt = 0;
#pragma unroll
  for (int i = 0; i < 16; ++i) {
    const float4 v = *reinterpret_cast<const float4*>(&row[i * 1024 + 4 * t]);
    const uint32_t nb = (v.x < 0.5f ? 1u : 0u) | (v.y < 0.5f ? 2u : 0u) |
                        (v.z < 0.5f ? 4u : 0u) | (v.w < 0.5f ? 8u : 0u);
    nib[i][t] = (uint8_t)nb;
    cnt += __popc(nb);
  }
  for (int o = 32; o > 0; o >>= 1) cnt += __shfl_down(cnt, o, 64);
  if (lane == 0) wcnt[t >> 6] = cnt;
  __syncthreads();
  if (t == 0) tot = wcnt[0] + wcnt[1] + wcnt[2] + wcnt[3];
  __syncthreads();
  const bool allb = (tot == N_);
  uint32_t* dst = mb + (size_t)bq * 512;
#pragma unroll
  for (int k = 0; k < 2; ++k) {
    const int w = k * 256 + t;
    const int i = w >> 5, tw = w & 31;
    const uint2 u = *reinterpret_cast<const uint2*>(&nib[i][8 * tw]);
    uint32_t y0 = u.x & 0x0F0F0F0Fu; y0 = y0 | (y0 >> 4);
    uint32_t y1 = u.y & 0x0F0F0F0Fu; y1 = y1 | (y1 >> 4);
    const uint32_t word = (y0 & 0xFFu) | (((y0 >> 16) & 0xFFu) << 8) |
                          ((y1 & 0xFFu) << 16) | (((y1 >> 16) & 0xFFu) << 24);
    dst[w] = allb ? 0u : word;
  }
}

// ---------------------------------------------------------------------------
// Kernel 2: Q projection with TRANSPOSED weights (coalesced). 4 rows/block.
// ---------------------------------------------------------------------------
__global__ __launch_bounds__(256) void qproj(const float* __restrict__ queries,
                                             const float* __restrict__ query_embed,
                                             const float* __restrict__ wqT,
                                             const float* __restrict__ bias,
                                             uint16_t* __restrict__ Qb) {
  const int r0 = blockIdx.x * 4;
  const int t = threadIdx.x;
  __shared__ float x[4][C_];
#pragma unroll
  for (int r = 0; r < 4; ++r)
    x[r][t] = queries[(size_t)(r0 + r) * C_ + t] + query_embed[(size_t)(r0 + r) * C_ + t];
  __syncthreads();
  float a0 = bias[t], a1 = a0, a2 = a0, a3 = a0;
#pragma unroll 4
  for (int j = 0; j < C_; ++j) {
    const float wv = wqT[(size_t)j * C_ + t];
    a0 = fmaf(x[0][j], wv, a0);
    a1 = fmaf(x[1][j], wv, a1);
    a2 = fmaf(x[2][j], wv, a2);
    a3 = fmaf(x[3][j], wv, a3);
  }
  const int h = t >> 5, dk = t & 31;
  const float r4[4] = {a0, a1, a2, a3};
#pragma unroll
  for (int r = 0; r < 4; ++r) {
    const int bq = r0 + r;
    const int b = bq >> 8, q = bq & 255;
    Qb[((size_t)(b * H_ + h) * Q_ + q) * D_ + dk] = f2bf(r4[r] * SCALE);
  }
}

// ---------------------------------------------------------------------------
// Kernel 3 (R4): K or V projection GEMM (template). 2-deep activation prefetch
// ring + 1-step-ahead weight ring, issued BEFORE the activation prefetch so
// (with in-order vmcnt retirement) the MFMA wait never drains the newest
// activation loads. Raw lgkm-only barrier; double-buffered LDS.
// Tile: 256 cout x 64 n. 8 waves = 4 cout-groups(64) x 2 n-groups(32).
// ISK=1: K' = wk@(vf+pe)+bk -> (B,N,C).  ISK=0: V' = wv@vf+bv -> (B,C,N).
// ---------------------------------------------------------------------------
template <int ISK>
__global__ __launch_bounds__(512, 4) void kvgemm(const float* __restrict__ vf,
                                                 const float* __restrict__ pe,
                                                 const uint16_t* __restrict__ wkv,
                                                 const float* __restrict__ bias,
                                                 uint16_t* __restrict__ outp) {
  const int bid = blockIdx.x;
  const int nb = bid & 255, b = bid >> 8;
  const int n0 = nb * 64;
  const int t = threadIdx.x, wid = t >> 6, lane = t & 63;
  const int g = lane >> 4, c15 = lane & 15;
  const int wc = wid & 3, wn = wid >> 2;

  __shared__ __align__(16) uint16_t Act[2][64][40];

  const float* X = vf + (size_t)b * C_ * N_;
  const float* P = pe + (size_t)b * C_ * N_;
  const uint16_t* Wbase = wkv + (ISK ? 0 : 256 * C_) + (size_t)(wc * 64 + c15) * C_;

  f32x4 acc[8];
  if (ISK) {
#pragma unroll
    for (int cf = 0; cf < 4; ++cf) {
      f32x4 iv;
#pragma unroll
      for (int j = 0; j < 4; ++j) iv[j] = bias[256 + wc * 64 + cf * 16 + 4 * g + j];
      acc[cf * 2 + 0] = iv;
      acc[cf * 2 + 1] = iv;
    }
  } else {
#pragma unroll
    for (int cf = 0; cf < 4; ++cf) {
      const float bv = bias[512 + wc * 64 + cf * 16 + c15];
      const f32x4 iv = {bv, bv, bv, bv};
      acc[0 * 4 + cf] = iv;
      acc[1 * 4 + cf] = iv;
    }
  }

  const int c2 = t >> 5, n2 = t & 31;
  const float* Xp = X + (size_t)(2 * c2) * N_ + n0 + 2 * n2;
  const float* Pp = P + (size_t)(2 * c2) * N_ + n0 + 2 * n2;
  const int cw2 = (c2 ^ (4 * ((n2 >> 2) & 3))) * 2;

  float2 ax0, ax1, ap0, ap1;
  float2 bx0, bx1, bp0, bp1;
  float2 cx0, cx1, cp0, cp1;
  bf16x8 WfA[4], WfB[4];

#define LOADSET(X0, X1, P0, P1, cc)                                         \
  {                                                                         \
    const float* xn_ = Xp + (size_t)(cc) * N_;                              \
    X0 = *(const float2*)xn_;                                               \
    X1 = *(const float2*)(xn_ + N_);                                        \
    if (ISK) {                                                              \
      const float* pn_ = Pp + (size_t)(cc) * N_;                            \
      P0 = *(const float2*)pn_;                                             \
      P1 = *(const float2*)(pn_ + N_);                                      \
    }                                                                       \
  }

#define LOADW(W, cc)                                                        \
  {                                                                         \
    _Pragma("unroll") for (int cf_ = 0; cf_ < 4; ++cf_)                     \
        W[cf_] = *(const bf16x8*)(Wbase + (size_t)cf_ * 16 * C_ + (cc) + g * 8); \
  }

#define WRITESET(buf, X0, X1, P0, P1)                                       \
  {                                                                         \
    uint32_t w0_, w1_;                                                      \
    if (ISK) {                                                              \
      w0_ = pk2(X0.x + P0.x, X1.x + P1.x);                                  \
      w1_ = pk2(X0.y + P0.y, X1.y + P1.y);                                  \
    } else {                                                                \
      w0_ = pk2(X0.x, X1.x);                                                \
      w1_ = pk2(X0.y, X1.y);                                                \
    }                                                                       \
    *(uint32_t*)&Act[buf][2 * n2][cw2] = w0_;                               \
    *(uint32_t*)&Act[buf][2 * n2 + 1][cw2] = w1_;                           \
  }

#define COMPUTE(buf, W)                                                     \
  {                                                                         \
    _Pragma("unroll") for (int nf_ = 0; nf_ < 2; ++nf_) {                   \
      const int r_ = wn * 32 + nf_ * 16 + c15;                              \
      const bf16x8 Bf_ = *(const bf16x8*)&Act[buf][r_][8 * (g ^ ((r_ >> 3) & 3))]; \
      if (ISK) {                                                            \
        _Pragma("unroll") for (int cf_ = 0; cf_ < 4; ++cf_)                 \
            acc[cf_ * 2 + nf_] = __builtin_amdgcn_mfma_f32_16x16x32_bf16(   \
                W[cf_], Bf_, acc[cf_ * 2 + nf_], 0, 0, 0);                  \
      } else {                                                              \
        _Pragma("unroll") for (int cf_ = 0; cf_ < 4; ++cf_)                 \
            acc[nf_ * 4 + cf_] = __builtin_amdgcn_mfma_f32_16x16x32_bf16(   \
                Bf_, W[cf_], acc[nf_ * 4 + cf_], 0, 0, 0);                  \
      }                                                                     \
    }                                                                       \
  }

  // prologue: ages (oldest->newest): WfA(0), S_a(0), S_b(32)
  LOADW(WfA, 0);
  LOADSET(ax0, ax1, ap0, ap1, 0);
  LOADSET(bx0, bx1, bp0, bp1, 32);

  // s=0
  LOADW(WfB, 32);
  WRITESET(0, ax0, ax1, ap0, ap1);
  LOADSET(cx0, cx1, cp0, cp1, 64);
  lgkm0_barrier();
  COMPUTE(0, WfA);
  // s=1
  LOADW(WfA, 64);
  WRITESET(1, bx0, bx1, bp0, bp1);
  LOADSET(ax0, ax1, ap0, ap1, 96);
  lgkm0_barrier();
  COMPUTE(1, WfB);
  // s=2
  LOADW(WfB, 96);
  WRITESET(0, cx0, cx1, cp0, cp1);
  LOADSET(bx0, bx1, bp0, bp1, 128);
  lgkm0_barrier();
  COMPUTE(0, WfA);
  // s=3
  LOADW(WfA, 128);
  WRITESET(1, ax0, ax1, ap0, ap1);
  LOADSET(cx0, cx1, cp0, cp1, 160);
  lgkm0_barrier();
  COMPUTE(1, WfB);
  // s=4
  LOADW(WfB, 160);
  WRITESET(0, bx0, bx1, bp0, bp1);
  LOADSET(ax0, ax1, ap0, ap1, 192);
  lgkm0_barrier();
  COMPUTE(0, WfA);
  // s=5
  LOADW(WfA, 192);
  WRITESET(1, cx0, cx1, cp0, cp1);
  LOADSET(bx0, bx1, bp0, bp1, 224);
  lgkm0_barrier();
  COMPUTE(1, WfB);
  // s=6
  LOADW(WfB, 224);
  WRITESET(0, ax0, ax1, ap0, ap1);
  lgkm0_barrier();
  COMPUTE(0, WfA);
  // s=7
  WRITESET(1, bx0, bx1, bp0, bp1);
  lgkm0_barrier();
  COMPUTE(1, WfB);

#undef LOADSET
#undef LOADW
#undef WRITESET
#undef COMPUTE

  if (ISK) {
    uint16_t* Kp = outp + (size_t)b * N_ * C_;
#pragma unroll
    for (int cf = 0; cf < 4; ++cf)
#pragma unroll
      for (int nf = 0; nf < 2; ++nf) {
        const f32x4 a = acc[cf * 2 + nf];
        uint2 pkv;
        pkv.x = pk2(a[0], a[1]);
        pkv.y = pk2(a[2], a[3]);
        *(uint2*)&Kp[(size_t)(n0 + wn * 32 + nf * 16 + c15) * C_ + wc * 64 + cf * 16 + 4 * g] = pkv;
      }
  } else {
    uint16_t* Vp = outp + (size_t)b * C_ * N_;
#pragma unroll
    for (int nf = 0; nf < 2; ++nf)
#pragma unroll
      for (int cf = 0; cf < 4; ++cf) {
        const f32x4 a = acc[nf * 4 + cf];
        uint2 pkv;
        pkv.x = pk2(a[0], a[1]);
        pkv.y = pk2(a[2], a[3]);
        *(uint2*)&Vp[(size_t)(wc * 64 + cf * 16 + c15) * N_ + n0 + wn * 32 + nf * 16 + 4 * g] = pkv;
      }
  }
}

// ---------------------------------------------------------------------------
// Kernel 4: attention over an N-chunk of 1024 keys, all 256 queries of one
// (b,h). Raw-barrier double-buffered K/V staging; mask words batched.
// ---------------------------------------------------------------------------
__global__ __launch_bounds__(512) void attn(const uint16_t* __restrict__ Qb,
                                            const uint16_t* __restrict__ Kb,
                                            const uint16_t* __restrict__ Vb,
                                            const uint32_t* __restrict__ mb,
                                            float* __restrict__ ctx_part,
                                            float* __restrict__ lsum_part) {
  const int bid = blockIdx.x;
  const int nc = bid & (NC_ - 1), h = (bid >> 4) & 7, b = bid >> 7;
  const int t = threadIdx.x, wid = t >> 6, lane = t & 63;
  const int g = lane >> 4, c15 = lane & 15;
  const int qw0 = wid * 32;
  const int nbase = nc * (N_ / NC_);
  constexpr int SS = (N_ / NC_) / 128;

  __shared__ __align__(16) uint16_t kst[2][128][40];
  __shared__ __align__(16) uint16_t vst[2][32][136];
  __shared__ __align__(16) uint16_t plds[8][32][40];

  const uint16_t* Qp = Qb + (size_t)(b * H_ + h) * Q_ * D_;
  bf16x8 qfr[2];
#pragma unroll
  for (int qf = 0; qf < 2; ++qf)
    qfr[qf] = *reinterpret_cast<const bf16x8*>(Qp + (size_t)(qw0 + qf * 16 + c15) * D_ + g * 8);

  f32x4 acc[2][2];
  const f32x4 zero4 = {0.f, 0.f, 0.f, 0.f};
#pragma unroll
  for (int qf = 0; qf < 2; ++qf)
#pragma unroll
    for (int dvf = 0; dvf < 2; ++dvf) acc[qf][dvf] = zero4;
  float lsum[2][4] = {};

  const uint32_t* mrow = mb + (size_t)b * Q_ * (N_ / 32);

  const int krow = t >> 2, kch = t & 3;
  const uint16_t* ksrc = Kb + ((size_t)(b * N_ + nbase + krow)) * C_ + h * D_ + kch * 8;
  const int vrow = t >> 4, vch = t & 15;
  const uint16_t* vsrc = Vb + ((size_t)(b * C_ + h * D_ + vrow)) * N_ + nbase + vch * 8;

  uint4 kreg = *(const uint4*)ksrc;
  uint4 vreg = *(const uint4*)vsrc;

  int cur = 0;
  for (int ss = 0; ss < SS; ++ss) {
    *(uint4*)&kst[cur][krow][kch * 8] = kreg;
    *(uint4*)&vst[cur][vrow][vch * 8] = vreg;
    if (ss < SS - 1) {  // prefetch next step's K/V (in flight across barrier)
      kreg = *(const uint4*)(ksrc + (size_t)(ss + 1) * 128 * C_);
      vreg = *(const uint4*)(vsrc + (ss + 1) * 128);
    }
    lgkm0_barrier();

    const int nstart = nbase + ss * 128;
#pragma unroll
    for (int half = 0; half < 2; ++half) {
      uint32_t mw[2][4][2];
#pragma unroll
      for (int qf = 0; qf < 2; ++qf)
#pragma unroll
        for (int j = 0; j < 4; ++j) {
          const int q = qw0 + qf * 16 + 4 * g + j;
          const uint2 u = *reinterpret_cast<const uint2*>(
              &mrow[(size_t)q * (N_ / 32) + (nstart >> 5) + half * 2]);
          mw[qf][j][0] = u.x;
          mw[qf][j][1] = u.y;
        }
#pragma unroll
      for (int s2 = 0; s2 < 2; ++s2) {
        const int sub = half * 2 + s2;
        const int nl0 = sub * 32;
        bf16x8 kfr[2];
#pragma unroll
        for (int nf = 0; nf < 2; ++nf)
          kfr[nf] = *reinterpret_cast<const bf16x8*>(&kst[cur][nl0 + nf * 16 + c15][g * 8]);
        f32x4 s[2][2];
#pragma unroll
        for (int qf = 0; qf < 2; ++qf)
#pragma unroll
          for (int nf = 0; nf < 2; ++nf)
            s[qf][nf] = __builtin_amdgcn_mfma_f32_16x16x32_bf16(qfr[qf], kfr[nf], zero4, 0, 0, 0);

#pragma unroll
        for (int qf = 0; qf < 2; ++qf) {
#pragma unroll
          for (int j = 0; j < 4; ++j) {
            const uint32_t wmask = mw[qf][j][s2];
#pragma unroll
            for (int nf = 0; nf < 2; ++nf) {
              const int bit = nf * 16 + c15;
              const float p = ((wmask >> bit) & 1u) ? 0.0f : __expf(s[qf][nf][j]);
              lsum[qf][j] += p;
              plds[wid][qf * 16 + 4 * g + j][nf * 16 + c15] = f2bf(p);
            }
          }
        }
        __asm__ volatile("s_waitcnt lgkmcnt(0)" ::: "memory");
#pragma unroll
        for (int qf = 0; qf < 2; ++qf) {
          const bf16x8 pa = *reinterpret_cast<const bf16x8*>(&plds[wid][qf * 16 + c15][g * 8]);
#pragma unroll
          for (int dvf = 0; dvf < 2; ++dvf) {
            const bf16x8 vb =
                *reinterpret_cast<const bf16x8*>(&vst[cur][dvf * 16 + c15][nl0 + g * 8]);
            acc[qf][dvf] = __builtin_amdgcn_mfma_f32_16x16x32_bf16(pa, vb, acc[qf][dvf], 0, 0, 0);
          }
        }
      }
    }
    __builtin_amdgcn_sched_barrier(0);
    cur ^= 1;
  }

#pragma unroll
  for (int qf = 0; qf < 2; ++qf)
#pragma unroll
    for (int j = 0; j < 4; ++j) {
      float v = lsum[qf][j];
      v += __shfl_xor(v, 1, 64);
      v += __shfl_xor(v, 2, 64);
      v += __shfl_xor(v, 4, 64);
      v += __shfl_xor(v, 8, 64);
      lsum[qf][j] = v;
    }

  float* cp = ctx_part + ((size_t)(b * H_ + h) * NC_ + nc) * Q_ * D_;
#pragma unroll
  for (int qf = 0; qf < 2; ++qf)
#pragma unroll
    for (int dvf = 0; dvf < 2; ++dvf)
#pragma unroll
      for (int j = 0; j < 4; ++j) {
        const int q = qw0 + qf * 16 + 4 * g + j;
        cp[(size_t)q * D_ + dvf * 16 + c15] = acc[qf][dvf][j];
      }
  if (c15 == 0) {
    float* lp = lsum_part + ((size_t)(b * H_ + h) * NC_ + nc) * Q_;
#pragma unroll
    for (int qf = 0; qf < 2; ++qf)
#pragma unroll
      for (int j = 0; j < 4; ++j) lp[qw0 + qf * 16 + 4 * g + j] = lsum[qf][j];
  }
}

// ---------------------------------------------------------------------------
// Kernel 5: combine partials + out_proj (TRANSPOSED weights) + residual + LN.
// ---------------------------------------------------------------------------
__global__ __launch_bounds__(256) void epilogue(const float* __restrict__ ctx_part,
                                                const float* __restrict__ lsum_part,
                                                const float* __restrict__ queries,
                                                const float* __restrict__ woT,
                                                const float* __restrict__ bo,
                                                const float* __restrict__ gamma,
                                                const float* __restrict__ beta,
                                                float* __restrict__ out) {
  const int bq = blockIdx.x;
  const int b = bq >> 8, q = bq & 255;
  const int t = threadIdx.x;
  const int h = t >> 5, dv = t & 31;
  float cs = 0.f, ls = 0.f;
  for (int k = 0; k < NC_; ++k) {
    cs += ctx_part[(((size_t)(b * H_ + h) * NC_ + k) * Q_ + q) * D_ + dv];
    ls += lsum_part[((size_t)(b * H_ + h) * NC_ + k) * Q_ + q];
  }
  __shared__ float ctxrow[C_];
  ctxrow[t] = cs / ls;
  __syncthreads();
  float acc = bo[t];
#pragma unroll 8
  for (int j = 0; j < C_; ++j) acc = fmaf(ctxrow[j], woT[(size_t)j * C_ + t], acc);
  const float x = queries[(size_t)bq * C_ + t] + acc;
  float s1 = x, s2 = x * x;
  for (int o = 32; o > 0; o >>= 1) {
    s1 += __shfl_down(s1, o, 64);
    s2 += __shfl_down(s2, o, 64);
  }
  __shared__ float r1[4], r2[4];
  if ((t & 63) == 0) { r1[t >> 6] = s1; r2[t >> 6] = s2; }
  __syncthreads();
  const float mu = (r1[0] + r1[1] + r1[2] + r1[3]) * (1.0f / C_);
  const float e2 = (r2[0] + r2[1] + r2[2] + r2[3]) * (1.0f / C_);
  const float var = e2 - mu * mu;
  out[(size_t)bq * C_ + t] = (x - mu) * rsqrtf(var + 1e-5f) * gamma[t] + beta[t];
}

extern "C" void kernel_launch(void* const* d_in, const int* in_sizes, int n_in,
                              void* d_out, int out_size, void* d_ws, size_t ws_size,
                              hipStream_t stream) {
  const float* queries    = (const float*)d_in[0];
  const float* vidfeat    = (const float*)d_in[1];
  const float* vidmask    = (const float*)d_in[2];
  const float* posembed   = (const float*)d_in[3];
  const float* queryembed = (const float*)d_in[4];
  const float* inw        = (const float*)d_in[5];
  const float* inb        = (const float*)d_in[6];
  const float* outw       = (const float*)d_in[7];
  const float* outb       = (const float*)d_in[8];
  const float* gamma      = (const float*)d_in[9];
  const float* beta       = (const float*)d_in[10];
  float* out = (float*)d_out;

  char* ws = (char*)d_ws;
  size_t off = 0;
  uint16_t* Qb = (uint16_t*)(ws + off); off += (size_t)B_ * H_ * Q_ * D_ * 2;
  uint16_t* Kb = (uint16_t*)(ws + off); off += (size_t)B_ * N_ * C_ * 2;
  uint16_t* Vb = (uint16_t*)(ws + off); off += (size_t)B_ * C_ * N_ * 2;
  uint32_t* mb = (uint32_t*)(ws + off); off += (size_t)B_ * Q_ * (N_ / 32) * 4;
  float* ctxp  = (float*)(ws + off);    off += (size_t)B_ * H_ * NC_ * Q_ * D_ * 4;
  float* lsump = (float*)(ws + off);    off += (size_t)B_ * H_ * NC_ * Q_ * 4;
  uint16_t* wkv = (uint16_t*)(ws + off); off += (size_t)512 * C_ * 2;
  float* wqT   = (float*)(ws + off);    off += (size_t)C_ * C_ * 4;
  float* woT   = (float*)(ws + off);    off += (size_t)C_ * C_ * 4;

  wprep<<<dim3(64), dim3(256), 0, stream>>>(inw, wkv);
  transpose256<<<dim3(64), dim3(256), 0, stream>>>(inw, wqT);
  transpose256<<<dim3(64), dim3(256), 0, stream>>>(outw, woT);
  pack_mask<<<dim3(B_ * Q_), dim3(256), 0, stream>>>(vidmask, mb);
  qproj<<<dim3(B_ * Q_ / 4), dim3(256), 0, stream>>>(queries, queryembed, wqT, inb, Qb);
  kvgemm<1><<<dim3(B_ * (N_ / 64)), dim3(512), 0, stream>>>(vidfeat, posembed, wkv, inb, Kb);
  kvgemm<0><<<dim3(B_ * (N_ / 64)), dim3(512), 0, stream>>>(vidfeat, posembed, wkv, inb, Vb);
  attn<<<dim3(B_ * H_ * NC_), dim3(512), 0, stream>>>(Qb, Kb, Vb, mb, ctxp, lsump);
  epilogue<<<dim3(B_ * Q_), dim3(256), 0, stream>>>(ctxp, lsump, queries, woT, outb, gamma, beta, out);
}

// Round 6
// 111.461 us; speedup vs baseline: 1.1603x; 1.1603x over previous
//
#include <hip/hip_runtime.h>
#include <stdint.h>

// CrossAttentionLayer: B=2, Q=256, N=16384, C=256, H=8, d=32
#define B_ 2
#define Q_ 256
#define N_ 16384
#define C_ 256
#define H_ 8
#define D_ 32
#define NC_ 32                      // attention split-N chunks (N/NC = 512 per block)
#define SCALE 0.17677669529663687f  // 1/sqrt(32)

typedef __bf16 bf16x8 __attribute__((ext_vector_type(8)));
typedef float f32x4 __attribute__((ext_vector_type(4)));

__device__ __forceinline__ uint16_t bfbits(float f) {
  union { __bf16 h; uint16_t u; } c;
  c.h = (__bf16)f;
  return c.u;
}
__device__ __forceinline__ uint16_t f2bf(float f) {
  union { float f; uint32_t u; } c; c.f = f;
  uint32_t r = c.u + 0x7FFFu + ((c.u >> 16) & 1u);  // RNE
  return (uint16_t)(r >> 16);
}
__device__ __forceinline__ uint32_t pk2(float a, float b) {
  return (uint32_t)f2bf(a) | ((uint32_t)f2bf(b) << 16);
}
__device__ __forceinline__ void lgkm0_barrier() {
  __builtin_amdgcn_sched_barrier(0);
  asm volatile("s_waitcnt lgkmcnt(0)" ::: "memory");
  __builtin_amdgcn_sched_barrier(0);
  __builtin_amdgcn_s_barrier();
  __builtin_amdgcn_sched_barrier(0);
}

// ---------------------------------------------------------------------------
// Kernel 1 "prep" (fused): blocks 0..95: in_proj_w (768x256) -> bf16;
// blocks 96..159: transpose out_proj_w -> woT; blocks 160..671: pack vid_mask
// -> bitmask (B,Q,N/32), bit=1 => blocked, with all-blocked fallback.
// ---------------------------------------------------------------------------
__global__ __launch_bounds__(256) void prep(const float* __restrict__ inw,
                                            const float* __restrict__ outw,
                                            const float* __restrict__ vm,
                                            uint16_t* __restrict__ wb,
                                            float* __restrict__ woT,
                                            uint32_t* __restrict__ mb) {
  __shared__ __align__(16) char sh[4352];
  const int bid = blockIdx.x;
  const int t = threadIdx.x;
  if (bid < 96) {
    const int i = (bid * 256 + t) * 8;
    const float4 a = *reinterpret_cast<const float4*>(inw + i);
    const float4 b = *reinterpret_cast<const float4*>(inw + i + 4);
    ushort4 lo = {bfbits(a.x), bfbits(a.y), bfbits(a.z), bfbits(a.w)};
    ushort4 hi = {bfbits(b.x), bfbits(b.y), bfbits(b.z), bfbits(b.w)};
    *reinterpret_cast<ushort4*>(wb + i) = lo;
    *reinterpret_cast<ushort4*>(wb + i + 4) = hi;
  } else if (bid < 160) {
    float(*s)[33] = reinterpret_cast<float(*)[33]>(sh);
    const int bb = bid - 96;
    const int bx = bb & 7, by = bb >> 3;
    const int r0 = by * 32, c0 = bx * 32;
    const int tr = t >> 5, tc = t & 31;
#pragma unroll
    for (int k = 0; k < 4; ++k)
      s[tr + 8 * k][tc] = outw[(size_t)(r0 + tr + 8 * k) * 256 + c0 + tc];
    __syncthreads();
#pragma unroll
    for (int k = 0; k < 4; ++k)
      woT[(size_t)(c0 + tr + 8 * k) * 256 + r0 + tc] = s[tc][tr + 8 * k];
  } else {
    uint8_t(*nib)[256] = reinterpret_cast<uint8_t(*)[256]>(sh);
    __shared__ int wcnt[4];
    __shared__ int tot;
    const int bq = bid - 160;
    const float* row = vm + (size_t)bq * N_;
    const int lane = t & 63;
    int cnt = 0;
#pragma unroll
    for (int i = 0; i < 16; ++i) {
      const float4 v = *reinterpret_cast<const float4*>(&row[i * 1024 + 4 * t]);
      const uint32_t nb = (v.x < 0.5f ? 1u : 0u) | (v.y < 0.5f ? 2u : 0u) |
                          (v.z < 0.5f ? 4u : 0u) | (v.w < 0.5f ? 8u : 0u);
      nib[i][t] = (uint8_t)nb;
      cnt += __popc(nb);
    }
    for (int o = 32; o > 0; o >>= 1) cnt += __shfl_down(cnt, o, 64);
    if (lane == 0) wcnt[t >> 6] = cnt;
    __syncthreads();
    if (t == 0) tot = wcnt[0] + wcnt[1] + wcnt[2] + wcnt[3];
    __syncthreads();
    const bool allb = (tot == N_);
    uint32_t* dst = mb + (size_t)bq * 512;
#pragma unroll
    for (int k = 0; k < 2; ++k) {
      const int w = k * 256 + t;
      const int i = w >> 5, tw = w & 31;
      const uint2 u = *reinterpret_cast<const uint2*>(&nib[i][8 * tw]);
      uint32_t y0 = u.x & 0x0F0F0F0Fu; y0 = y0 | (y0 >> 4);
      uint32_t y1 = u.y & 0x0F0F0F0Fu; y1 = y1 | (y1 >> 4);
      const uint32_t word = (y0 & 0xFFu) | (((y0 >> 16) & 0xFFu) << 8) |
                            ((y1 & 0xFFu) << 16) | (((y1 >> 16) & 0xFFu) << 24);
      dst[w] = allb ? 0u : word;
    }
  }
}

// ---------------------------------------------------------------------------
// Kernel 2 "kvqproj": blocks 0..1023: K/V projection, BIG-STAGE structure —
// the whole 256-cin x 32-n activation tile is staged to LDS in ONE load burst
// (16 independent float4 loads/thread), one barrier, then 8 cin-steps of pure
// LDS+MFMA. Blocks 1024..1031: Q projection via MFMA (64 q-rows each).
//   K' = wk@(vf+pe)+bk -> (B,N,C);  V' = wv@vf+bv -> (B,C,N);
//   Qb = ((queries+qe)@wq^T + bq)*SCALE -> (B,H,Q,32)
// LDS: lds[s][0..31][.] = XP (or XQ rows 0..63), lds[s][32..63][.] = XV.
// Col swizzle: col' = col ^ (8*((row>>3)&3)) -> conflict-light b128 reads.
// ---------------------------------------------------------------------------
__global__ __launch_bounds__(512) void kvqproj(const float* __restrict__ vf,
                                               const float* __restrict__ pe,
                                               const float* __restrict__ queries,
                                               const float* __restrict__ qembed,
                                               const uint16_t* __restrict__ wkv,
                                               const float* __restrict__ bias,
                                               uint16_t* __restrict__ Kb,
                                               uint16_t* __restrict__ Vb,
                                               uint16_t* __restrict__ Qb) {
  __shared__ __align__(16) uint16_t lds[8][64][40];
  const int bid = blockIdx.x;
  const int t = threadIdx.x, wid = t >> 6, lane = t & 63;
  const int g = lane >> 4, c15 = lane & 15;

  if (bid < 1024) {
    const int nb = bid & 511, b = bid >> 9;
    const int n0 = nb * 32;
    // ---- stage: full 256-cin x 32-n tile, one burst ----
    const int cin = t >> 1, nh = (t & 1) * 16;
    const int s = cin >> 5, cl = cin & 31;
    const float* Xrow = vf + ((size_t)b * C_ + cin) * N_ + n0 + nh;
    const float* Prow = pe + ((size_t)b * C_ + cin) * N_ + n0 + nh;
    float4 xr4[4], pr4[4];
#pragma unroll
    for (int k = 0; k < 4; ++k) xr4[k] = reinterpret_cast<const float4*>(Xrow)[k];
#pragma unroll
    for (int k = 0; k < 4; ++k) pr4[k] = reinterpret_cast<const float4*>(Prow)[k];
    const float* xf = reinterpret_cast<const float*>(xr4);
    const float* pf = reinterpret_cast<const float*>(pr4);
#pragma unroll
    for (int i = 0; i < 16; ++i) {
      const int n = nh + i;
      const int col = cl ^ (8 * ((n >> 3) & 3));
      lds[s][n][col] = bfbits(xf[i] + pf[i]);       // XP
      lds[s][32 + n][col] = bfbits(xf[i]);          // XV
    }
    lgkm0_barrier();

    // ---- compute: waves 0-3 K, waves 4-7 V; wave = 64 cout x 32 n ----
    const bool isK = wid < 4;
    const int wc = wid & 3;
    const uint16_t* W = wkv + (isK ? 256 * C_ : 512 * C_);
    f32x4 acc[4][2];
    if (isK) {
#pragma unroll
      for (int cf = 0; cf < 4; ++cf) {
        f32x4 iv;
#pragma unroll
        for (int j = 0; j < 4; ++j) iv[j] = bias[256 + wc * 64 + cf * 16 + 4 * g + j];
        acc[cf][0] = iv;
        acc[cf][1] = iv;
      }
    } else {
#pragma unroll
      for (int cf = 0; cf < 4; ++cf) {
        const float bv = bias[512 + wc * 64 + cf * 16 + c15];
        const f32x4 iv = {bv, bv, bv, bv};
        acc[0][cf] = iv;   // acc[nf][cf] for V (nf<2 uses rows 0,1)
        acc[1][cf] = iv;
      }
    }
#pragma unroll
    for (int s8 = 0; s8 < 8; ++s8) {
      bf16x8 Wf[4];
#pragma unroll
      for (int cf = 0; cf < 4; ++cf)
        Wf[cf] = *reinterpret_cast<const bf16x8*>(
            W + (size_t)(wc * 64 + cf * 16 + c15) * C_ + s8 * 32 + g * 8);
      if (isK) {
#pragma unroll
        for (int nf = 0; nf < 2; ++nf) {
          const int r = nf * 16 + c15;
          const bf16x8 Bf = *reinterpret_cast<const bf16x8*>(
              &lds[s8][r][8 * (g ^ ((r >> 3) & 3))]);
#pragma unroll
          for (int cf = 0; cf < 4; ++cf)
            acc[cf][nf] = __builtin_amdgcn_mfma_f32_16x16x32_bf16(Wf[cf], Bf, acc[cf][nf], 0, 0, 0);
        }
      } else {
#pragma unroll
        for (int nf = 0; nf < 2; ++nf) {
          const int r = nf * 16 + c15;
          const bf16x8 Af = *reinterpret_cast<const bf16x8*>(
              &lds[s8][32 + r][8 * (g ^ ((r >> 3) & 3))]);
#pragma unroll
          for (int cf = 0; cf < 4; ++cf)
            acc[nf][cf] = __builtin_amdgcn_mfma_f32_16x16x32_bf16(Af, Wf[cf], acc[nf][cf], 0, 0, 0);
        }
      }
    }
    // ---- store ----
    if (isK) {  // D[row=cout][col=n] -> K (B,N,C) packed uint2 (4 cout)
      uint16_t* Kp = Kb + (size_t)b * N_ * C_;
#pragma unroll
      for (int cf = 0; cf < 4; ++cf)
#pragma unroll
        for (int nf = 0; nf < 2; ++nf) {
          const f32x4 a = acc[cf][nf];
          uint2 pkv;
          pkv.x = pk2(a[0], a[1]);
          pkv.y = pk2(a[2], a[3]);
          *reinterpret_cast<uint2*>(
              &Kp[(size_t)(n0 + nf * 16 + c15) * C_ + wc * 64 + cf * 16 + 4 * g]) = pkv;
        }
    } else {  // D[row=n][col=cout] -> V (B,C,N) packed uint2 (4 n)
      uint16_t* Vp = Vb + (size_t)b * C_ * N_;
#pragma unroll
      for (int nf = 0; nf < 2; ++nf)
#pragma unroll
        for (int cf = 0; cf < 4; ++cf) {
          const f32x4 a = acc[nf][cf];
          uint2 pkv;
          pkv.x = pk2(a[0], a[1]);
          pkv.y = pk2(a[2], a[3]);
          *reinterpret_cast<uint2*>(
              &Vp[(size_t)(wc * 64 + cf * 16 + c15) * N_ + n0 + nf * 16 + 4 * g]) = pkv;
        }
    }
  } else {
    // ---- Q projection: 8 blocks x 64 q-rows ----
    const int qb = bid - 1024;
    const int q0g = qb * 64;
    const int b = q0g >> 8, q0 = q0g & 255;
    const int r = t >> 3, c0 = (t & 7) * 32, s = t & 7;
    const float* Qrow = queries + (size_t)(q0g + r) * C_ + c0;
    const float* Erow = qembed + (size_t)(q0g + r) * C_ + c0;
#pragma unroll
    for (int ph = 0; ph < 2; ++ph) {  // 2 phases to cap VGPR
      float4 a4[4], e4[4];
#pragma unroll
      for (int k = 0; k < 4; ++k) a4[k] = reinterpret_cast<const float4*>(Qrow + ph * 16)[k];
#pragma unroll
      for (int k = 0; k < 4; ++k) e4[k] = reinterpret_cast<const float4*>(Erow + ph * 16)[k];
      const float* af = reinterpret_cast<const float*>(a4);
      const float* ef = reinterpret_cast<const float*>(e4);
#pragma unroll
      for (int i = 0; i < 16; ++i) {
        const int cl = ph * 16 + i;
        const int col = cl ^ (8 * ((r >> 3) & 3));
        lds[s][r][col] = bfbits(af[i] + ef[i]);
      }
      __builtin_amdgcn_sched_barrier(0);
    }
    lgkm0_barrier();

    const int w = wid;  // head = w, cout slice w*32
    f32x4 acc[4][2];
#pragma unroll
    for (int nf = 0; nf < 2; ++nf) {
      const float bv = bias[w * 32 + nf * 16 + c15];
      const f32x4 iv = {bv, bv, bv, bv};
#pragma unroll
      for (int qf = 0; qf < 4; ++qf) acc[qf][nf] = iv;
    }
#pragma unroll
    for (int s8 = 0; s8 < 8; ++s8) {
      bf16x8 Bf[2];
#pragma unroll
      for (int nf = 0; nf < 2; ++nf)
        Bf[nf] = *reinterpret_cast<const bf16x8*>(
            wkv + (size_t)(w * 32 + nf * 16 + c15) * C_ + s8 * 32 + g * 8);
#pragma unroll
      for (int qf = 0; qf < 4; ++qf) {
        const int rr = qf * 16 + c15;
        const bf16x8 Af = *reinterpret_cast<const bf16x8*>(
            &lds[s8][rr][8 * (g ^ ((rr >> 3) & 3))]);
#pragma unroll
        for (int nf = 0; nf < 2; ++nf)
          acc[qf][nf] = __builtin_amdgcn_mfma_f32_16x16x32_bf16(Af, Bf[nf], acc[qf][nf], 0, 0, 0);
      }
    }
    // D[row=q][col=cout]; h = w, dk = nf*16+c15
#pragma unroll
    for (int qf = 0; qf < 4; ++qf)
#pragma unroll
      for (int nf = 0; nf < 2; ++nf)
#pragma unroll
        for (int j = 0; j < 4; ++j) {
          const int q = q0 + qf * 16 + 4 * g + j;
          const int dk = nf * 16 + c15;
          Qb[((size_t)(b * H_ + w) * Q_ + q) * D_ + dk] = f2bf(acc[qf][nf][j] * SCALE);
        }
  }
}

// ---------------------------------------------------------------------------
// Kernel 3: attention over an N-chunk of 512 keys, all 256 queries of one
// (b,h). Raw-barrier double-buffered K/V staging; mask words batched.
// ---------------------------------------------------------------------------
__global__ __launch_bounds__(512) void attn(const uint16_t* __restrict__ Qb,
                                            const uint16_t* __restrict__ Kb,
                                            const uint16_t* __restrict__ Vb,
                                            const uint32_t* __restrict__ mb,
                                            float* __restrict__ ctx_part,
                                            float* __restrict__ lsum_part) {
  const int bid = blockIdx.x;
  const int nc = bid & 31, h = (bid >> 5) & 7, b = bid >> 8;
  const int t = threadIdx.x, wid = t >> 6, lane = t & 63;
  const int g = lane >> 4, c15 = lane & 15;
  const int qw0 = wid * 32;
  const int nbase = nc * (N_ / NC_);
  constexpr int SS = (N_ / NC_) / 128;

  __shared__ __align__(16) uint16_t kst[2][128][40];
  __shared__ __align__(16) uint16_t vst[2][32][136];
  __shared__ __align__(16) uint16_t plds[8][32][40];

  const uint16_t* Qp = Qb + (size_t)(b * H_ + h) * Q_ * D_;
  bf16x8 qfr[2];
#pragma unroll
  for (int qf = 0; qf < 2; ++qf)
    qfr[qf] = *reinterpret_cast<const bf16x8*>(Qp + (size_t)(qw0 + qf * 16 + c15) * D_ + g * 8);

  f32x4 acc[2][2];
  const f32x4 zero4 = {0.f, 0.f, 0.f, 0.f};
#pragma unroll
  for (int qf = 0; qf < 2; ++qf)
#pragma unroll
    for (int dvf = 0; dvf < 2; ++dvf) acc[qf][dvf] = zero4;
  float lsum[2][4] = {};

  const uint32_t* mrow = mb + (size_t)b * Q_ * (N_ / 32);

  const int krow = t >> 2, kch = t & 3;
  const uint16_t* ksrc = Kb + ((size_t)(b * N_ + nbase + krow)) * C_ + h * D_ + kch * 8;
  const int vrow = t >> 4, vch = t & 15;
  const uint16_t* vsrc = Vb + ((size_t)(b * C_ + h * D_ + vrow)) * N_ + nbase + vch * 8;

  uint4 kreg = *(const uint4*)ksrc;
  uint4 vreg = *(const uint4*)vsrc;

  int cur = 0;
  for (int ss = 0; ss < SS; ++ss) {
    *(uint4*)&kst[cur][krow][kch * 8] = kreg;
    *(uint4*)&vst[cur][vrow][vch * 8] = vreg;
    if (ss < SS - 1) {
      kreg = *(const uint4*)(ksrc + (size_t)(ss + 1) * 128 * C_);
      vreg = *(const uint4*)(vsrc + (ss + 1) * 128);
    }
    lgkm0_barrier();

    const int nstart = nbase + ss * 128;
#pragma unroll
    for (int half = 0; half < 2; ++half) {
      uint32_t mw[2][4][2];
#pragma unroll
      for (int qf = 0; qf < 2; ++qf)
#pragma unroll
        for (int j = 0; j < 4; ++j) {
          const int q = qw0 + qf * 16 + 4 * g + j;
          const uint2 u = *reinterpret_cast<const uint2*>(
              &mrow[(size_t)q * (N_ / 32) + (nstart >> 5) + half * 2]);
          mw[qf][j][0] = u.x;
          mw[qf][j][1] = u.y;
        }
#pragma unroll
      for (int s2 = 0; s2 < 2; ++s2) {
        const int sub = half * 2 + s2;
        const int nl0 = sub * 32;
        bf16x8 kfr[2];
#pragma unroll
        for (int nf = 0; nf < 2; ++nf)
          kfr[nf] = *reinterpret_cast<const bf16x8*>(&kst[cur][nl0 + nf * 16 + c15][g * 8]);
        f32x4 s[2][2];
#pragma unroll
        for (int qf = 0; qf < 2; ++qf)
#pragma unroll
          for (int nf = 0; nf < 2; ++nf)
            s[qf][nf] = __builtin_amdgcn_mfma_f32_16x16x32_bf16(qfr[qf], kfr[nf], zero4, 0, 0, 0);

#pragma unroll
        for (int qf = 0; qf < 2; ++qf) {
#pragma unroll
          for (int j = 0; j < 4; ++j) {
            const uint32_t wmask = mw[qf][j][s2];
#pragma unroll
            for (int nf = 0; nf < 2; ++nf) {
              const int bit = nf * 16 + c15;
              const float p = ((wmask >> bit) & 1u) ? 0.0f : __expf(s[qf][nf][j]);
              lsum[qf][j] += p;
              plds[wid][qf * 16 + 4 * g + j][nf * 16 + c15] = f2bf(p);
            }
          }
        }
        __asm__ volatile("s_waitcnt lgkmcnt(0)" ::: "memory");
#pragma unroll
        for (int qf = 0; qf < 2; ++qf) {
          const bf16x8 pa = *reinterpret_cast<const bf16x8*>(&plds[wid][qf * 16 + c15][g * 8]);
#pragma unroll
          for (int dvf = 0; dvf < 2; ++dvf) {
            const bf16x8 vb =
                *reinterpret_cast<const bf16x8*>(&vst[cur][dvf * 16 + c15][nl0 + g * 8]);
            acc[qf][dvf] = __builtin_amdgcn_mfma_f32_16x16x32_bf16(pa, vb, acc[qf][dvf], 0, 0, 0);
          }
        }
      }
    }
    __builtin_amdgcn_sched_barrier(0);
    cur ^= 1;
  }

#pragma unroll
  for (int qf = 0; qf < 2; ++qf)
#pragma unroll
    for (int j = 0; j < 4; ++j) {
      float v = lsum[qf][j];
      v += __shfl_xor(v, 1, 64);
      v += __shfl_xor(v, 2, 64);
      v += __shfl_xor(v, 4, 64);
      v += __shfl_xor(v, 8, 64);
      lsum[qf][j] = v;
    }

  float* cp = ctx_part + ((size_t)(b * H_ + h) * NC_ + nc) * Q_ * D_;
#pragma unroll
  for (int qf = 0; qf < 2; ++qf)
#pragma unroll
    for (int dvf = 0; dvf < 2; ++dvf)
#pragma unroll
      for (int j = 0; j < 4; ++j) {
        const int q = qw0 + qf * 16 + 4 * g + j;
        cp[(size_t)q * D_ + dvf * 16 + c15] = acc[qf][dvf][j];
      }
  if (c15 == 0) {
    float* lp = lsum_part + ((size_t)(b * H_ + h) * NC_ + nc) * Q_;
#pragma unroll
    for (int qf = 0; qf < 2; ++qf)
#pragma unroll
      for (int j = 0; j < 4; ++j) lp[qw0 + qf * 16 + 4 * g + j] = lsum[qf][j];
  }
}

// ---------------------------------------------------------------------------
// Kernel 4: combine partials + out_proj (TRANSPOSED weights) + residual + LN.
// ---------------------------------------------------------------------------
__global__ __launch_bounds__(256) void epilogue(const float* __restrict__ ctx_part,
                                                const float* __restrict__ lsum_part,
                                                const float* __restrict__ queries,
                                                const float* __restrict__ woT,
                                                const float* __restrict__ bo,
                                                const float* __restrict__ gamma,
                                                const float* __restrict__ beta,
                                                float* __restrict__ out) {
  const int bq = blockIdx.x;
  const int b = bq >> 8, q = bq & 255;
  const int t = threadIdx.x;
  const int h = t >> 5, dv = t & 31;
  float cs = 0.f, ls = 0.f;
  for (int k = 0; k < NC_; ++k) {
    cs += ctx_part[(((size_t)(b * H_ + h) * NC_ + k) * Q_ + q) * D_ + dv];
    ls += lsum_part[((size_t)(b * H_ + h) * NC_ + k) * Q_ + q];
  }
  __shared__ float ctxrow[C_];
  ctxrow[t] = cs / ls;
  __syncthreads();
  float acc = bo[t];
#pragma unroll 8
  for (int j = 0; j < C_; ++j) acc = fmaf(ctxrow[j], woT[(size_t)j * C_ + t], acc);
  const float x = queries[(size_t)bq * C_ + t] + acc;
  float s1 = x, s2 = x * x;
  for (int o = 32; o > 0; o >>= 1) {
    s1 += __shfl_down(s1, o, 64);
    s2 += __shfl_down(s2, o, 64);
  }
  __shared__ float r1[4], r2[4];
  if ((t & 63) == 0) { r1[t >> 6] = s1; r2[t >> 6] = s2; }
  __syncthreads();
  const float mu = (r1[0] + r1[1] + r1[2] + r1[3]) * (1.0f / C_);
  const float e2 = (r2[0] + r2[1] + r2[2] + r2[3]) * (1.0f / C_);
  const float var = e2 - mu * mu;
  out[(size_t)bq * C_ + t] = (x - mu) * rsqrtf(var + 1e-5f) * gamma[t] + beta[t];
}

extern "C" void kernel_launch(void* const* d_in, const int* in_sizes, int n_in,
                              void* d_out, int out_size, void* d_ws, size_t ws_size,
                              hipStream_t stream) {
  const float* queries    = (const float*)d_in[0];
  const float* vidfeat    = (const float*)d_in[1];
  const float* vidmask    = (const float*)d_in[2];
  const float* posembed   = (const float*)d_in[3];
  const float* queryembed = (const float*)d_in[4];
  const float* inw        = (const float*)d_in[5];
  const float* inb        = (const float*)d_in[6];
  const float* outw       = (const float*)d_in[7];
  const float* outb       = (const float*)d_in[8];
  const float* gamma      = (const float*)d_in[9];
  const float* beta       = (const float*)d_in[10];
  float* out = (float*)d_out;

  char* ws = (char*)d_ws;
  size_t off = 0;
  uint16_t* Qb = (uint16_t*)(ws + off); off += (size_t)B_ * H_ * Q_ * D_ * 2;
  uint16_t* Kb = (uint16_t*)(ws + off); off += (size_t)B_ * N_ * C_ * 2;
  uint16_t* Vb = (uint16_t*)(ws + off); off += (size_t)B_ * C_ * N_ * 2;
  uint32_t* mb = (uint32_t*)(ws + off); off += (size_t)B_ * Q_ * (N_ / 32) * 4;
  float* ctxp  = (float*)(ws + off);    off += (size_t)B_ * H_ * NC_ * Q_ * D_ * 4;
  float* lsump = (float*)(ws + off);    off += (size_t)B_ * H_ * NC_ * Q_ * 4;
  uint16_t* wkv = (uint16_t*)(ws + off); off += (size_t)768 * C_ * 2;
  float* woT   = (float*)(ws + off);    off += (size_t)C_ * C_ * 4;

  prep<<<dim3(672), dim3(256), 0, stream>>>(inw, outw, vidmask, wkv, woT, mb);
  kvqproj<<<dim3(1032), dim3(512), 0, stream>>>(vidfeat, posembed, queries, queryembed,
                                                wkv, inb, Kb, Vb, Qb);
  attn<<<dim3(B_ * H_ * NC_), dim3(512), 0, stream>>>(Qb, Kb, Vb, mb, ctxp, lsump);
  epilogue<<<dim3(B_ * Q_), dim3(256), 0, stream>>>(ctxp, lsump, queries, woT, outb, gamma, beta, out);
}

// Round 7
// 108.066 us; speedup vs baseline: 1.1967x; 1.0314x over previous
//
#include <hip/hip_runtime.h>
#include <stdint.h>

// CrossAttentionLayer: B=2, Q=256, N=16384, C=256, H=8, d=32
#define B_ 2
#define Q_ 256
#define N_ 16384
#define C_ 256
#define H_ 8
#define D_ 32
#define NC_ 32                      // attention split-N chunks (N/NC = 512 per block)
#define SCALE 0.17677669529663687f  // 1/sqrt(32)

typedef __bf16 bf16x8 __attribute__((ext_vector_type(8)));
typedef float f32x4 __attribute__((ext_vector_type(4)));

__device__ __forceinline__ uint16_t bfbits(float f) {
  union { __bf16 h; uint16_t u; } c;
  c.h = (__bf16)f;
  return c.u;
}
__device__ __forceinline__ uint16_t f2bf(float f) {
  union { float f; uint32_t u; } c; c.f = f;
  uint32_t r = c.u + 0x7FFFu + ((c.u >> 16) & 1u);  // RNE
  return (uint16_t)(r >> 16);
}
__device__ __forceinline__ uint32_t pk2(float a, float b) {
  return (uint32_t)f2bf(a) | ((uint32_t)f2bf(b) << 16);
}
__device__ __forceinline__ void lgkm0_barrier() {
  __builtin_amdgcn_sched_barrier(0);
  asm volatile("s_waitcnt lgkmcnt(0)" ::: "memory");
  __builtin_amdgcn_sched_barrier(0);
  __builtin_amdgcn_s_barrier();
  __builtin_amdgcn_sched_barrier(0);
}

// ---------------------------------------------------------------------------
// Kernel 1 "prep" (fused): blocks 0..95: in_proj_w (768x256) -> bf16;
// blocks 96..159: transpose out_proj_w -> woT; blocks 160..671: pack vid_mask
// -> bitmask (B,Q,N/32), bit=1 => blocked, with all-blocked fallback.
// ---------------------------------------------------------------------------
__global__ __launch_bounds__(256) void prep(const float* __restrict__ inw,
                                            const float* __restrict__ outw,
                                            const float* __restrict__ vm,
                                            uint16_t* __restrict__ wb,
                                            float* __restrict__ woT,
                                            uint32_t* __restrict__ mb) {
  __shared__ __align__(16) char sh[4352];
  const int bid = blockIdx.x;
  const int t = threadIdx.x;
  if (bid < 96) {
    const int i = (bid * 256 + t) * 8;
    const float4 a = *reinterpret_cast<const float4*>(inw + i);
    const float4 b = *reinterpret_cast<const float4*>(inw + i + 4);
    ushort4 lo = {bfbits(a.x), bfbits(a.y), bfbits(a.z), bfbits(a.w)};
    ushort4 hi = {bfbits(b.x), bfbits(b.y), bfbits(b.z), bfbits(b.w)};
    *reinterpret_cast<ushort4*>(wb + i) = lo;
    *reinterpret_cast<ushort4*>(wb + i + 4) = hi;
  } else if (bid < 160) {
    float(*s)[33] = reinterpret_cast<float(*)[33]>(sh);
    const int bb = bid - 96;
    const int bx = bb & 7, by = bb >> 3;
    const int r0 = by * 32, c0 = bx * 32;
    const int tr = t >> 5, tc = t & 31;
#pragma unroll
    for (int k = 0; k < 4; ++k)
      s[tr + 8 * k][tc] = outw[(size_t)(r0 + tr + 8 * k) * 256 + c0 + tc];
    __syncthreads();
#pragma unroll
    for (int k = 0; k < 4; ++k)
      woT[(size_t)(c0 + tr + 8 * k) * 256 + r0 + tc] = s[tc][tr + 8 * k];
  } else {
    uint8_t(*nib)[256] = reinterpret_cast<uint8_t(*)[256]>(sh);
    __shared__ int wcnt[4];
    __shared__ int tot;
    const int bq = bid - 160;
    const float* row = vm + (size_t)bq * N_;
    const int lane = t & 63;
    int cnt = 0;
#pragma unroll
    for (int i = 0; i < 16; ++i) {
      const float4 v = *reinterpret_cast<const float4*>(&row[i * 1024 + 4 * t]);
      const uint32_t nb = (v.x < 0.5f ? 1u : 0u) | (v.y < 0.5f ? 2u : 0u) |
                          (v.z < 0.5f ? 4u : 0u) | (v.w < 0.5f ? 8u : 0u);
      nib[i][t] = (uint8_t)nb;
      cnt += __popc(nb);
    }
    for (int o = 32; o > 0; o >>= 1) cnt += __shfl_down(cnt, o, 64);
    if (lane == 0) wcnt[t >> 6] = cnt;
    __syncthreads();
    if (t == 0) tot = wcnt[0] + wcnt[1] + wcnt[2] + wcnt[3];
    __syncthreads();
    const bool allb = (tot == N_);
    uint32_t* dst = mb + (size_t)bq * 512;
#pragma unroll
    for (int k = 0; k < 2; ++k) {
      const int w = k * 256 + t;
      const int i = w >> 5, tw = w & 31;
      const uint2 u = *reinterpret_cast<const uint2*>(&nib[i][8 * tw]);
      uint32_t y0 = u.x & 0x0F0F0F0Fu; y0 = y0 | (y0 >> 4);
      uint32_t y1 = u.y & 0x0F0F0F0Fu; y1 = y1 | (y1 >> 4);
      const uint32_t word = (y0 & 0xFFu) | (((y0 >> 16) & 0xFFu) << 8) |
                            ((y1 & 0xFFu) << 16) | (((y1 >> 16) & 0xFFu) << 24);
      dst[w] = allb ? 0u : word;
    }
  }
}

// ---------------------------------------------------------------------------
// Kernel 2 "kvqproj" (R6 rewrite): persistent pipelined K/V projection.
// Blocks 0..255 (1/CU): 4 tiles of (256 cin x 32 n) each, grid-stride.
//   - weights held ENTIRELY in registers (loaded once from L2): steady-state
//     vmcnt counter carries only the activation stream.
//   - double-buffered LDS; per tile: COMPUTE(cur) overlaps in-flight loads of
//     tile+1; then STAGE_WRITE(next); issue loads tile+2; lgkm-only barrier.
//   - staging: thread loads 4cin x 1n scalar quads (wave-coalesced), packs to
//     bf16, ds_write_b64; swizzle byte^=((n<<1)&31)<<4 => <=2-way conflicts
//     on both writes and b128 fragment reads.
// Blocks 256..263: Q projection via MFMA (64 q-rows each).
// ---------------------------------------------------------------------------
__global__ __launch_bounds__(512, 1) void kvqproj(const float* __restrict__ vf,
                                                  const float* __restrict__ pe,
                                                  const float* __restrict__ queries,
                                                  const float* __restrict__ qembed,
                                                  const uint16_t* __restrict__ wkv,
                                                  const float* __restrict__ bias,
                                                  uint16_t* __restrict__ Kb,
                                                  uint16_t* __restrict__ Vb,
                                                  uint16_t* __restrict__ Qb) {
  const int bid = blockIdx.x;
  const int t = threadIdx.x, wid = t >> 6, lane = t & 63;
  const int g = lane >> 4, c15 = lane & 15;

  if (bid < 256) {
    __shared__ __align__(16) uint16_t XPs[2][32][256];
    __shared__ __align__(16) uint16_t XVs[2][32][256];
    char* xpb[2] = {(char*)&XPs[0][0][0], (char*)&XPs[1][0][0]};
    char* xvb[2] = {(char*)&XVs[0][0][0], (char*)&XVs[1][0][0]};

    const bool isK = wid < 4;
    const int wc = wid & 3;

    // ---- weights -> registers (32 x 16B from L2) ----
    const uint16_t* Wbase = wkv + (isK ? 256 * C_ : 512 * C_) + (size_t)(wc * 64 + c15) * C_;
    bf16x8 Wreg[4][8];
#pragma unroll
    for (int cf = 0; cf < 4; ++cf)
#pragma unroll
      for (int s8 = 0; s8 < 8; ++s8)
        Wreg[cf][s8] = *reinterpret_cast<const bf16x8*>(Wbase + (size_t)cf * 16 * C_ + s8 * 32 + g * 8);

    // ---- bias init values ----
    f32x4 bk4[4];
    float bv4[4];
#pragma unroll
    for (int cf = 0; cf < 4; ++cf) {
      if (isK) {
#pragma unroll
        for (int j = 0; j < 4; ++j) bk4[cf][j] = bias[256 + wc * 64 + cf * 16 + 4 * g + j];
      } else {
        bv4[cf] = bias[512 + wc * 64 + cf * 16 + c15];
      }
    }

    const int sn = t & 31;   // n within tile
    const int qi = t >> 5;   // 0..15 (cin quad base qi*4 within 64-group)
    const int swz = ((sn << 1) & 31) << 4;
    const int g0 = bid * 4;  // first tile index; tiles g0..g0+3

    float xr[4][4], pr[4][4];
    f32x4 acc[8];

#define STAGE_LOAD(G)                                                        \
    {                                                                        \
      const int b_ = (G) >> 9;                                               \
      const int n0_ = ((G) & 511) * 32;                                      \
      const float* Xb_ = vf + (size_t)b_ * C_ * N_ + n0_ + sn;               \
      const float* Pb_ = pe + (size_t)b_ * C_ * N_ + n0_ + sn;               \
      _Pragma("unroll") for (int q = 0; q < 4; ++q)                          \
        _Pragma("unroll") for (int j = 0; j < 4; ++j) {                      \
          const size_t ro_ = (size_t)(q * 64 + qi * 4 + j) * N_;             \
          xr[q][j] = Xb_[ro_];                                               \
          pr[q][j] = Pb_[ro_];                                               \
        }                                                                    \
    }

#define STAGE_WRITE(buf)                                                     \
    {                                                                        \
      _Pragma("unroll") for (int q = 0; q < 4; ++q) {                        \
        const int cb_ = (q * 64 + qi * 4) * 2;                               \
        uint2 wxp_, wxv_;                                                    \
        wxp_.x = pk2(xr[q][0] + pr[q][0], xr[q][1] + pr[q][1]);              \
        wxp_.y = pk2(xr[q][2] + pr[q][2], xr[q][3] + pr[q][3]);              \
        wxv_.x = pk2(xr[q][0], xr[q][1]);                                    \
        wxv_.y = pk2(xr[q][2], xr[q][3]);                                    \
        *(uint2*)(xpb[buf] + sn * 512 + (cb_ ^ swz)) = wxp_;                 \
        *(uint2*)(xvb[buf] + sn * 512 + (cb_ ^ swz)) = wxv_;                 \
      }                                                                      \
    }

#define ACCINIT()                                                            \
    {                                                                        \
      if (isK) {                                                             \
        _Pragma("unroll") for (int cf = 0; cf < 4; ++cf) {                   \
          acc[cf * 2 + 0] = bk4[cf];                                         \
          acc[cf * 2 + 1] = bk4[cf];                                         \
        }                                                                    \
      } else {                                                               \
        _Pragma("unroll") for (int cf = 0; cf < 4; ++cf) {                   \
          const f32x4 iv_ = {bv4[cf], bv4[cf], bv4[cf], bv4[cf]};            \
          acc[0 * 4 + cf] = iv_;                                             \
          acc[1 * 4 + cf] = iv_;                                             \
        }                                                                    \
      }                                                                      \
    }

#define COMPUTE(buf)                                                         \
    {                                                                        \
      _Pragma("unroll") for (int s8 = 0; s8 < 8; ++s8)                       \
        _Pragma("unroll") for (int nf = 0; nf < 2; ++nf) {                   \
          const int nr_ = nf * 16 + c15;                                     \
          const int off_ = nr_ * 512 + ((s8 * 64 + g * 16) ^ (((nr_ << 1) & 31) << 4)); \
          if (isK) {                                                         \
            const bf16x8 Bf_ = *(const bf16x8*)(xpb[buf] + off_);            \
            _Pragma("unroll") for (int cf = 0; cf < 4; ++cf)                 \
              acc[cf * 2 + nf] = __builtin_amdgcn_mfma_f32_16x16x32_bf16(    \
                  Wreg[cf][s8], Bf_, acc[cf * 2 + nf], 0, 0, 0);             \
          } else {                                                           \
            const bf16x8 Af_ = *(const bf16x8*)(xvb[buf] + off_);            \
            _Pragma("unroll") for (int cf = 0; cf < 4; ++cf)                 \
              acc[nf * 4 + cf] = __builtin_amdgcn_mfma_f32_16x16x32_bf16(    \
                  Af_, Wreg[cf][s8], acc[nf * 4 + cf], 0, 0, 0);             \
          }                                                                  \
        }                                                                    \
    }

#define STORE(G)                                                             \
    {                                                                        \
      const int b_ = (G) >> 9;                                               \
      const int n0_ = ((G) & 511) * 32;                                      \
      if (isK) {                                                             \
        uint16_t* Kp_ = Kb + (size_t)b_ * N_ * C_;                           \
        _Pragma("unroll") for (int cf = 0; cf < 4; ++cf)                     \
          _Pragma("unroll") for (int nf = 0; nf < 2; ++nf) {                 \
            const f32x4 a_ = acc[cf * 2 + nf];                               \
            uint2 pkv_;                                                      \
            pkv_.x = pk2(a_[0], a_[1]);                                      \
            pkv_.y = pk2(a_[2], a_[3]);                                      \
            *(uint2*)&Kp_[(size_t)(n0_ + nf * 16 + c15) * C_ + wc * 64 + cf * 16 + 4 * g] = pkv_; \
          }                                                                  \
      } else {                                                               \
        uint16_t* Vp_ = Vb + (size_t)b_ * C_ * N_;                           \
        _Pragma("unroll") for (int nf = 0; nf < 2; ++nf)                     \
          _Pragma("unroll") for (int cf = 0; cf < 4; ++cf) {                 \
            const f32x4 a_ = acc[nf * 4 + cf];                               \
            uint2 pkv_;                                                      \
            pkv_.x = pk2(a_[0], a_[1]);                                      \
            pkv_.y = pk2(a_[2], a_[3]);                                      \
            *(uint2*)&Vp_[(size_t)(wc * 64 + cf * 16 + c15) * N_ + n0_ + nf * 16 + 4 * g] = pkv_; \
          }                                                                  \
      }                                                                      \
    }

    // ---- pipeline: 4 tiles, double-buffered, one lgkm barrier per tile ----
    STAGE_LOAD(g0);
    STAGE_WRITE(0);          // implicit vmcnt wait for tile g0 loads only
    STAGE_LOAD(g0 + 1);
    lgkm0_barrier();

    ACCINIT(); COMPUTE(0); STORE(g0);
    STAGE_WRITE(1);          // waits tile g0+1 loads (in flight during compute)
    STAGE_LOAD(g0 + 2);
    lgkm0_barrier();

    ACCINIT(); COMPUTE(1); STORE(g0 + 1);
    STAGE_WRITE(0);
    STAGE_LOAD(g0 + 3);
    lgkm0_barrier();

    ACCINIT(); COMPUTE(0); STORE(g0 + 2);
    STAGE_WRITE(1);
    lgkm0_barrier();

    ACCINIT(); COMPUTE(1); STORE(g0 + 3);

#undef STAGE_LOAD
#undef STAGE_WRITE
#undef ACCINIT
#undef COMPUTE
#undef STORE
  } else {
    // ---- Q projection: 8 blocks x 64 q-rows ----
    __shared__ __align__(16) uint16_t qlds[8][64][40];
    const int qb = bid - 256;
    const int q0g = qb * 64;
    const int b = q0g >> 8, q0 = q0g & 255;
    const int r = t >> 3, c0 = (t & 7) * 32, s = t & 7;
    const float* Qrow = queries + (size_t)(q0g + r) * C_ + c0;
    const float* Erow = qembed + (size_t)(q0g + r) * C_ + c0;
#pragma unroll
    for (int ph = 0; ph < 2; ++ph) {
      float4 a4[4], e4[4];
#pragma unroll
      for (int k = 0; k < 4; ++k) a4[k] = reinterpret_cast<const float4*>(Qrow + ph * 16)[k];
#pragma unroll
      for (int k = 0; k < 4; ++k) e4[k] = reinterpret_cast<const float4*>(Erow + ph * 16)[k];
      const float* af = reinterpret_cast<const float*>(a4);
      const float* ef = reinterpret_cast<const float*>(e4);
#pragma unroll
      for (int i = 0; i < 16; ++i) {
        const int cl = ph * 16 + i;
        const int col = cl ^ (8 * ((r >> 3) & 3));
        qlds[s][r][col] = bfbits(af[i] + ef[i]);
      }
      __builtin_amdgcn_sched_barrier(0);
    }
    lgkm0_barrier();

    const int w = wid;  // head = w
    f32x4 acc[4][2];
#pragma unroll
    for (int nf = 0; nf < 2; ++nf) {
      const float bv = bias[w * 32 + nf * 16 + c15];
      const f32x4 iv = {bv, bv, bv, bv};
#pragma unroll
      for (int qf = 0; qf < 4; ++qf) acc[qf][nf] = iv;
    }
#pragma unroll
    for (int s8 = 0; s8 < 8; ++s8) {
      bf16x8 Bf[2];
#pragma unroll
      for (int nf = 0; nf < 2; ++nf)
        Bf[nf] = *reinterpret_cast<const bf16x8*>(
            wkv + (size_t)(w * 32 + nf * 16 + c15) * C_ + s8 * 32 + g * 8);
#pragma unroll
      for (int qf = 0; qf < 4; ++qf) {
        const int rr = qf * 16 + c15;
        const bf16x8 Af = *reinterpret_cast<const bf16x8*>(
            &qlds[s8][rr][8 * (g ^ ((rr >> 3) & 3))]);
#pragma unroll
        for (int nf = 0; nf < 2; ++nf)
          acc[qf][nf] = __builtin_amdgcn_mfma_f32_16x16x32_bf16(Af, Bf[nf], acc[qf][nf], 0, 0, 0);
      }
    }
#pragma unroll
    for (int qf = 0; qf < 4; ++qf)
#pragma unroll
      for (int nf = 0; nf < 2; ++nf)
#pragma unroll
        for (int j = 0; j < 4; ++j) {
          const int q = q0 + qf * 16 + 4 * g + j;
          const int dk = nf * 16 + c15;
          Qb[((size_t)(b * H_ + w) * Q_ + q) * D_ + dk] = f2bf(acc[qf][nf][j] * SCALE);
        }
  }
}

// ---------------------------------------------------------------------------
// Kernel 3: attention over an N-chunk of 512 keys, all 256 queries of one
// (b,h). Raw-barrier double-buffered K/V staging; mask words batched.
// ---------------------------------------------------------------------------
__global__ __launch_bounds__(512) void attn(const uint16_t* __restrict__ Qb,
                                            const uint16_t* __restrict__ Kb,
                                            const uint16_t* __restrict__ Vb,
                                            const uint32_t* __restrict__ mb,
                                            float* __restrict__ ctx_part,
                                            float* __restrict__ lsum_part) {
  const int bid = blockIdx.x;
  const int nc = bid & 31, h = (bid >> 5) & 7, b = bid >> 8;
  const int t = threadIdx.x, wid = t >> 6, lane = t & 63;
  const int g = lane >> 4, c15 = lane & 15;
  const int qw0 = wid * 32;
  const int nbase = nc * (N_ / NC_);
  constexpr int SS = (N_ / NC_) / 128;

  __shared__ __align__(16) uint16_t kst[2][128][40];
  __shared__ __align__(16) uint16_t vst[2][32][136];
  __shared__ __align__(16) uint16_t plds[8][32][40];

  const uint16_t* Qp = Qb + (size_t)(b * H_ + h) * Q_ * D_;
  bf16x8 qfr[2];
#pragma unroll
  for (int qf = 0; qf < 2; ++qf)
    qfr[qf] = *reinterpret_cast<const bf16x8*>(Qp + (size_t)(qw0 + qf * 16 + c15) * D_ + g * 8);

  f32x4 acc[2][2];
  const f32x4 zero4 = {0.f, 0.f, 0.f, 0.f};
#pragma unroll
  for (int qf = 0; qf < 2; ++qf)
#pragma unroll
    for (int dvf = 0; dvf < 2; ++dvf) acc[qf][dvf] = zero4;
  float lsum[2][4] = {};

  const uint32_t* mrow = mb + (size_t)b * Q_ * (N_ / 32);

  const int krow = t >> 2, kch = t & 3;
  const uint16_t* ksrc = Kb + ((size_t)(b * N_ + nbase + krow)) * C_ + h * D_ + kch * 8;
  const int vrow = t >> 4, vch = t & 15;
  const uint16_t* vsrc = Vb + ((size_t)(b * C_ + h * D_ + vrow)) * N_ + nbase + vch * 8;

  uint4 kreg = *(const uint4*)ksrc;
  uint4 vreg = *(const uint4*)vsrc;

  int cur = 0;
  for (int ss = 0; ss < SS; ++ss) {
    *(uint4*)&kst[cur][krow][kch * 8] = kreg;
    *(uint4*)&vst[cur][vrow][vch * 8] = vreg;
    if (ss < SS - 1) {
      kreg = *(const uint4*)(ksrc + (size_t)(ss + 1) * 128 * C_);
      vreg = *(const uint4*)(vsrc + (ss + 1) * 128);
    }
    lgkm0_barrier();

    const int nstart = nbase + ss * 128;
#pragma unroll
    for (int half = 0; half < 2; ++half) {
      uint32_t mw[2][4][2];
#pragma unroll
      for (int qf = 0; qf < 2; ++qf)
#pragma unroll
        for (int j = 0; j < 4; ++j) {
          const int q = qw0 + qf * 16 + 4 * g + j;
          const uint2 u = *reinterpret_cast<const uint2*>(
              &mrow[(size_t)q * (N_ / 32) + (nstart >> 5) + half * 2]);
          mw[qf][j][0] = u.x;
          mw[qf][j][1] = u.y;
        }
#pragma unroll
      for (int s2 = 0; s2 < 2; ++s2) {
        const int sub = half * 2 + s2;
        const int nl0 = sub * 32;
        bf16x8 kfr[2];
#pragma unroll
        for (int nf = 0; nf < 2; ++nf)
          kfr[nf] = *reinterpret_cast<const bf16x8*>(&kst[cur][nl0 + nf * 16 + c15][g * 8]);
        f32x4 s[2][2];
#pragma unroll
        for (int qf = 0; qf < 2; ++qf)
#pragma unroll
          for (int nf = 0; nf < 2; ++nf)
            s[qf][nf] = __builtin_amdgcn_mfma_f32_16x16x32_bf16(qfr[qf], kfr[nf], zero4, 0, 0, 0);

#pragma unroll
        for (int qf = 0; qf < 2; ++qf) {
#pragma unroll
          for (int j = 0; j < 4; ++j) {
            const uint32_t wmask = mw[qf][j][s2];
#pragma unroll
            for (int nf = 0; nf < 2; ++nf) {
              const int bit = nf * 16 + c15;
              const float p = ((wmask >> bit) & 1u) ? 0.0f : __expf(s[qf][nf][j]);
              lsum[qf][j] += p;
              plds[wid][qf * 16 + 4 * g + j][nf * 16 + c15] = f2bf(p);
            }
          }
        }
        __asm__ volatile("s_waitcnt lgkmcnt(0)" ::: "memory");
#pragma unroll
        for (int qf = 0; qf < 2; ++qf) {
          const bf16x8 pa = *reinterpret_cast<const bf16x8*>(&plds[wid][qf * 16 + c15][g * 8]);
#pragma unroll
          for (int dvf = 0; dvf < 2; ++dvf) {
            const bf16x8 vb =
                *reinterpret_cast<const bf16x8*>(&vst[cur][dvf * 16 + c15][nl0 + g * 8]);
            acc[qf][dvf] = __builtin_amdgcn_mfma_f32_16x16x32_bf16(pa, vb, acc[qf][dvf], 0, 0, 0);
          }
        }
      }
    }
    __builtin_amdgcn_sched_barrier(0);
    cur ^= 1;
  }

#pragma unroll
  for (int qf = 0; qf < 2; ++qf)
#pragma unroll
    for (int j = 0; j < 4; ++j) {
      float v = lsum[qf][j];
      v += __shfl_xor(v, 1, 64);
      v += __shfl_xor(v, 2, 64);
      v += __shfl_xor(v, 4, 64);
      v += __shfl_xor(v, 8, 64);
      lsum[qf][j] = v;
    }

  float* cp = ctx_part + ((size_t)(b * H_ + h) * NC_ + nc) * Q_ * D_;
#pragma unroll
  for (int qf = 0; qf < 2; ++qf)
#pragma unroll
    for (int dvf = 0; dvf < 2; ++dvf)
#pragma unroll
      for (int j = 0; j < 4; ++j) {
        const int q = qw0 + qf * 16 + 4 * g + j;
        cp[(size_t)q * D_ + dvf * 16 + c15] = acc[qf][dvf][j];
      }
  if (c15 == 0) {
    float* lp = lsum_part + ((size_t)(b * H_ + h) * NC_ + nc) * Q_;
#pragma unroll
    for (int qf = 0; qf < 2; ++qf)
#pragma unroll
      for (int j = 0; j < 4; ++j) lp[qw0 + qf * 16 + 4 * g + j] = lsum[qf][j];
  }
}

// ---------------------------------------------------------------------------
// Kernel 4: combine partials + out_proj (TRANSPOSED weights) + residual + LN.
// ---------------------------------------------------------------------------
__global__ __launch_bounds__(256) void epilogue(const float* __restrict__ ctx_part,
                                                const float* __restrict__ lsum_part,
                                                const float* __restrict__ queries,
                                                const float* __restrict__ woT,
                                                const float* __restrict__ bo,
                                                const float* __restrict__ gamma,
                                                const float* __restrict__ beta,
                                                float* __restrict__ out) {
  const int bq = blockIdx.x;
  const int b = bq >> 8, q = bq & 255;
  const int t = threadIdx.x;
  const int h = t >> 5, dv = t & 31;
  float cs = 0.f, ls = 0.f;
  for (int k = 0; k < NC_; ++k) {
    cs += ctx_part[(((size_t)(b * H_ + h) * NC_ + k) * Q_ + q) * D_ + dv];
    ls += lsum_part[((size_t)(b * H_ + h) * NC_ + k) * Q_ + q];
  }
  __shared__ float ctxrow[C_];
  ctxrow[t] = cs / ls;
  __syncthreads();
  float acc = bo[t];
#pragma unroll 8
  for (int j = 0; j < C_; ++j) acc = fmaf(ctxrow[j], woT[(size_t)j * C_ + t], acc);
  const float x = queries[(size_t)bq * C_ + t] + acc;
  float s1 = x, s2 = x * x;
  for (int o = 32; o > 0; o >>= 1) {
    s1 += __shfl_down(s1, o, 64);
    s2 += __shfl_down(s2, o, 64);
  }
  __shared__ float r1[4], r2[4];
  if ((t & 63) == 0) { r1[t >> 6] = s1; r2[t >> 6] = s2; }
  __syncthreads();
  const float mu = (r1[0] + r1[1] + r1[2] + r1[3]) * (1.0f / C_);
  const float e2 = (r2[0] + r2[1] + r2[2] + r2[3]) * (1.0f / C_);
  const float var = e2 - mu * mu;
  out[(size_t)bq * C_ + t] = (x - mu) * rsqrtf(var + 1e-5f) * gamma[t] + beta[t];
}

extern "C" void kernel_launch(void* const* d_in, const int* in_sizes, int n_in,
                              void* d_out, int out_size, void* d_ws, size_t ws_size,
                              hipStream_t stream) {
  const float* queries    = (const float*)d_in[0];
  const float* vidfeat    = (const float*)d_in[1];
  const float* vidmask    = (const float*)d_in[2];
  const float* posembed   = (const float*)d_in[3];
  const float* queryembed = (const float*)d_in[4];
  const float* inw        = (const float*)d_in[5];
  const float* inb        = (const float*)d_in[6];
  const float* outw       = (const float*)d_in[7];
  const float* outb       = (const float*)d_in[8];
  const float* gamma      = (const float*)d_in[9];
  const float* beta       = (const float*)d_in[10];
  float* out = (float*)d_out;

  char* ws = (char*)d_ws;
  size_t off = 0;
  uint16_t* Qb = (uint16_t*)(ws + off); off += (size_t)B_ * H_ * Q_ * D_ * 2;
  uint16_t* Kb = (uint16_t*)(ws + off); off += (size_t)B_ * N_ * C_ * 2;
  uint16_t* Vb = (uint16_t*)(ws + off); off += (size_t)B_ * C_ * N_ * 2;
  uint32_t* mb = (uint32_t*)(ws + off); off += (size_t)B_ * Q_ * (N_ / 32) * 4;
  float* ctxp  = (float*)(ws + off);    off += (size_t)B_ * H_ * NC_ * Q_ * D_ * 4;
  float* lsump = (float*)(ws + off);    off += (size_t)B_ * H_ * NC_ * Q_ * 4;
  uint16_t* wkv = (uint16_t*)(ws + off); off += (size_t)768 * C_ * 2;
  float* woT   = (float*)(ws + off);    off += (size_t)C_ * C_ * 4;

  prep<<<dim3(672), dim3(256), 0, stream>>>(inw, outw, vidmask, wkv, woT, mb);
  kvqproj<<<dim3(264), dim3(512), 0, stream>>>(vidfeat, posembed, queries, queryembed,
                                               wkv, inb, Kb, Vb, Qb);
  attn<<<dim3(B_ * H_ * NC_), dim3(512), 0, stream>>>(Qb, Kb, Vb, mb, ctxp, lsump);
  epilogue<<<dim3(B_ * Q_), dim3(256), 0, stream>>>(ctxp, lsump, queries, woT, outb, gamma, beta, out);
}